// Round 4
// baseline (852.910 us; speedup 1.0000x reference)
//
#include <hip/hip_runtime.h>
#include <hip/hip_bf16.h>
#include <math.h>

#define B_ 128
#define L_ 50
#define D_ 128
#define S_ 12
#define NEG_INF_ -9e15f

typedef __attribute__((ext_vector_type(8))) short short8;
typedef __attribute__((ext_vector_type(8))) _Float16 half8;
typedef __attribute__((ext_vector_type(4))) float f32x4;

static __device__ __forceinline__ float4 ld4(const float* p){ return *(const float4*)p; }
static __device__ __forceinline__ float2 ld2(const float* p){ return *(const float2*)p; }
static __device__ __forceinline__ float lrelu(float x){ return x >= 0.f ? x : 0.2f*x; }
static __device__ __forceinline__ short f2bf(float x){
  return __builtin_bit_cast(short, __float2bfloat16(x));   // RNE
}
static __device__ __forceinline__ unsigned pack2h(float a, float b){
  union { _Float16 h[2]; unsigned u; } v;
  v.h[0] = (_Float16)a; v.h[1] = (_Float16)b; return v.u;
}

// ---------------------------------------------------------------------------
// Local aggregator: 4-edge-type GAT over the session graph. One block per b.
// ---------------------------------------------------------------------------
__global__ __launch_bounds__(256) void local_agg_kernel(
    const int* __restrict__ inputs, const int* __restrict__ adj,
    const float* __restrict__ emb,
    const float* __restrict__ a0, const float* __restrict__ a1,
    const float* __restrict__ a2, const float* __restrict__ a3,
    float* __restrict__ hlocal_out)
{
  __shared__ float hs[L_][129];
  __shared__ float alds[4][129];
  __shared__ float att[L_][51];
  const int b = blockIdx.x, tid = threadIdx.x;

  if (tid < 128){
    alds[0][tid] = a0[tid]; alds[1][tid] = a1[tid];
    alds[2][tid] = a2[tid]; alds[3][tid] = a3[tid];
  }
  for (int i = tid; i < L_*D_; i += 256){
    int r = i >> 7, d = i & 127;
    hs[r][d] = emb[(size_t)inputs[b*L_ + r]*D_ + d];
  }
  __syncthreads();

  for (int pth = tid; pth < L_*L_; pth += 256){
    int i = pth / L_, j = pth % L_;
    int at = adj[b*L_*L_ + pth];
    float lg = NEG_INF_;
    if (at >= 1 && at <= 4){
      const float* av = alds[at-1];
      float acc = 0.f;
      #pragma unroll 4
      for (int d = 0; d < D_; ++d) acc = fmaf(hs[i][d]*hs[j][d], av[d], acc);
      lg = lrelu(acc);
    }
    att[i][j] = lg;
  }
  __syncthreads();

  if (tid < L_){
    float m = -1e30f;
    for (int j = 0; j < L_; ++j) m = fmaxf(m, att[tid][j]);
    float sum = 0.f;
    for (int j = 0; j < L_; ++j){ float e = expf(att[tid][j]-m); att[tid][j] = e; sum += e; }
    float inv = 1.f/sum;
    for (int j = 0; j < L_; ++j) att[tid][j] *= inv;
  }
  __syncthreads();

  for (int i2 = tid; i2 < L_*D_; i2 += 256){
    int r = i2 >> 7, d = i2 & 127;
    float acc = 0.f;
    #pragma unroll 5
    for (int j = 0; j < L_; ++j) acc = fmaf(att[r][j], hs[j][d], acc);
    hlocal_out[(size_t)b*L_*D_ + i2] = acc;
  }
}

// ---------------------------------------------------------------------------
// Session mean
// ---------------------------------------------------------------------------
__global__ __launch_bounds__(128) void sum_item_kernel(
    const int* __restrict__ item, const int* __restrict__ mask,
    const float* __restrict__ emb, float* __restrict__ sum_it)
{
  const int b = blockIdx.x, d = threadIdx.x;
  float acc = 0.f, cnt = 0.f;
  for (int l = 0; l < L_; ++l){
    float mf = (float)mask[b*L_ + l];
    acc = fmaf(mf, emb[(size_t)item[b*L_+l]*D_ + d], acc);
    cnt += mf;
  }
  sum_it[b*D_ + d] = acc / cnt;
}

// ---------------------------------------------------------------------------
// Neighbor expansion
// ---------------------------------------------------------------------------
__global__ void build_nbr_kernel(const int* __restrict__ src_ids, int n,
                                 const int* __restrict__ adj_all,
                                 const float* __restrict__ num_w,
                                 int* __restrict__ out_ids, float* __restrict__ out_w)
{
  int t = blockIdx.x*blockDim.x + threadIdx.x;
  if (t >= n) return;
  int parent = src_ids[t / S_];
  int s = t % S_;
  out_ids[t] = adj_all[(size_t)parent*S_ + s];
  out_w[t]   = num_w[(size_t)parent*S_ + s];
}

// ---------------------------------------------------------------------------
// Pack gw1[hop][k<128][d] into MFMA B-fragment order (bf16).
// Fragment (t,n): lane l, slot j <- gw1[k = t*32 + (l>>4)*8 + j][n*16 + (l&15)]
// ---------------------------------------------------------------------------
__global__ void prep_gw1frag_kernel(const float* __restrict__ gw1, short* __restrict__ outf){
  int idx = blockIdx.x*256 + threadIdx.x;     // 0..2047 = t(4) x n(8) x lane(64)
  int hop = blockIdx.y;
  int lane = idx & 63, n = (idx >> 6) & 7, t = idx >> 9;
  int g4 = lane >> 4, col = lane & 15;
  const float* g1 = gw1 + (size_t)hop*129*128;
  size_t base = (size_t)hop*16384 + ((size_t)(t*8 + n)*64 + lane)*8;
  #pragma unroll
  for (int j = 0; j < 8; ++j){
    int k = t*32 + g4*8 + j;
    outf[base + j] = f2bf(g1[(size_t)k*128 + n*16 + col]);
  }
}

// ---------------------------------------------------------------------------
// Pack gw3[hop][k<256][d] into MFMA B-fragment order (f16).
// Fragment (kt,n): lane l, slot j <- gw3[k = kt*32 + (l>>4)*8 + j][n*16 + (l&15)]
// ---------------------------------------------------------------------------
__global__ void prep_gw3frag_kernel(const float* __restrict__ gw3, _Float16* __restrict__ outf){
  int idx = blockIdx.x*256 + threadIdx.x;     // 0..4095 = kt(8) x n(8) x lane(64)
  int hop = blockIdx.y;
  int lane = idx & 63, n = (idx >> 6) & 7, kt = idx >> 9;
  int g4 = lane >> 4, col = lane & 15;
  const float* g3 = gw3 + (size_t)hop*256*128;
  size_t base = (size_t)hop*32768 + ((size_t)(kt*8 + n)*64 + lane)*8;
  #pragma unroll
  for (int j = 0; j < 8; ++j){
    int k = kt*32 + g4*8 + j;
    outf[base + j] = (_Float16)g3[(size_t)k*128 + n*16 + col];
  }
}

// ---------------------------------------------------------------------------
// GlobalAggregator, MFMA version v2.
// Block = 256 thr = 4 waves; each WAVE owns one 16-pair group.
// Phase 1 (per pair): stage B bf16 MFMA (A = si*nv gathers, B = gw1f frags),
//   nw rank-1 fp32, scores+softmax, stage C attn-gather -> catl row (f16) into
//   wave-private LDS [16][264] (pad 8 halves -> ~2-way bank aliasing).
// Phase 2 (per group): stage D as [16x256]@[256x128] f16 MFMA, B = gw3f frags
//   streamed from L2 (64 loads / 16 pairs vs 128/pair before).
// C/D frag layout (HW-verified R3): col=lane&15, row=(lane>>4)*4+reg.
// ---------------------------------------------------------------------------
template<bool SV_IDS, bool NV_IDS>
__global__ __launch_bounds__(256, 3) void gagg_mfma_kernel(
    const float* __restrict__ emb,
    const int*   __restrict__ sv_ids, const float* __restrict__ sv_vals,
    const int*   __restrict__ nv_ids, const float* __restrict__ nv_vals,
    const float* __restrict__ nw,     const float* __restrict__ sum_it,
    const short* __restrict__ gw1f,   const float* __restrict__ gw1_last,
    const float* __restrict__ gw2,    const _Float16* __restrict__ gw3f,
    float* __restrict__ outp, int M)
{
  __shared__ _Float16 catl[4][16][264];      // 33792 B
  const int tid  = threadIdx.x;
  const int wid  = tid >> 6;
  const int lane = tid & 63;
  const int g4   = lane >> 4;
  const int col  = lane & 15;
  const int pgrp = (blockIdx.x*4 + wid)*16;  // this wave's 16-pair group

  const short8* g1fp = (const short8*)gw1f;
  // hoisted per-lane weight columns (pair-invariant)
  float g2v[8], glv[8];
  #pragma unroll
  for (int n = 0; n < 8; ++n){
    g2v[n] = gw2[n*16 + col];
    glv[n] = gw1_last[n*16 + col];
  }

  // ---------------- phase 1: stages B + C for 16 pairs ----------------
  for (int np = 0; np < 16; ++np){
    const int p = pgrp + np;
    const int b = p / M;

    // stage B: A-frag build + MFMA
    const int   srow  = col;               // A row = s (12..15 masked)
    const int   sc_   = srow < S_ ? srow : 0;
    const float* nvrow = NV_IDS
        ? emb + (size_t)nv_ids[p*S_ + sc_] * D_
        : nv_vals + ((size_t)p*S_ + sc_) * D_;
    const float* sib = sum_it + b*D_;

    f32x4 acc[8];
    #pragma unroll
    for (int n = 0; n < 8; ++n) acc[n] = (f32x4){0.f,0.f,0.f,0.f};

    #pragma unroll
    for (int t = 0; t < 4; ++t){
      short8 af = (short8){0,0,0,0,0,0,0,0};
      if (srow < S_){
        const int k0 = t*32 + g4*8;
        float4 s0 = ld4(sib + k0), s1 = ld4(sib + k0 + 4);
        float4 v0 = ld4(nvrow + k0), v1 = ld4(nvrow + k0 + 4);
        af[0] = f2bf(s0.x * v0.x);
        af[1] = f2bf(s0.y * v0.y);
        af[2] = f2bf(s0.z * v0.z);
        af[3] = f2bf(s0.w * v0.w);
        af[4] = f2bf(s1.x * v1.x);
        af[5] = f2bf(s1.y * v1.y);
        af[6] = f2bf(s1.z * v1.z);
        af[7] = f2bf(s1.w * v1.w);
      }
      #pragma unroll
      for (int n = 0; n < 8; ++n)
        acc[n] = __builtin_amdgcn_mfma_f32_16x16x32_bf16(af, g1fp[(t*8+n)*64 + lane], acc[n], 0, 0, 0);
    }

    // nw rank-1 (fp32) + scores
    float nwv[4];
    #pragma unroll
    for (int r = 0; r < 4; ++r){
      int s = g4*4 + r;
      nwv[r] = nw[p*S_ + (s < S_ ? s : 0)];
    }
    float sc4[4];
    #pragma unroll
    for (int r = 0; r < 4; ++r){
      float pr = 0.f;
      #pragma unroll
      for (int n = 0; n < 8; ++n){
        float tv = acc[n][r] + nwv[r]*glv[n];
        pr = fmaf(lrelu(tv), g2v[n], pr);
      }
      pr += __shfl_xor(pr, 1); pr += __shfl_xor(pr, 2);
      pr += __shfl_xor(pr, 4); pr += __shfl_xor(pr, 8);
      sc4[r] = pr;
    }
    float w[S_];
    {
      float ss[S_];
      #pragma unroll
      for (int grp = 0; grp < 3; ++grp)
        #pragma unroll
        for (int r = 0; r < 4; ++r)
          ss[grp*4 + r] = __shfl(sc4[r], grp*16);
      float m = -1e30f;
      #pragma unroll
      for (int s = 0; s < S_; ++s) m = fmaxf(m, ss[s]);
      float sum = 0.f;
      #pragma unroll
      for (int s = 0; s < S_; ++s){ ss[s] = expf(ss[s]-m); sum += ss[s]; }
      float inv = 1.f/sum;
      #pragma unroll
      for (int s = 0; s < S_; ++s) w[s] = ss[s]*inv;
    }

    // stage C: attn-weighted nv + sv -> f16 catl row in LDS
    float2 agg = {0.f, 0.f};
    #pragma unroll
    for (int s = 0; s < S_; ++s){
      const float* row = NV_IDS ? emb + (size_t)nv_ids[p*S_+s]*D_
                                : nv_vals + ((size_t)p*S_+s)*D_;
      float2 v = ld2(row + 2*lane);
      agg.x = fmaf(w[s], v.x, agg.x);
      agg.y = fmaf(w[s], v.y, agg.y);
    }
    const float* svrow = SV_IDS ? emb + (size_t)sv_ids[p]*D_
                                : sv_vals + (size_t)p*D_;
    float2 sv2 = ld2(svrow + 2*lane);

    *(unsigned*)&catl[wid][np][2*lane]       = pack2h(sv2.x, sv2.y);
    *(unsigned*)&catl[wid][np][D_ + 2*lane]  = pack2h(agg.x, agg.y);
  }

  asm volatile("s_waitcnt lgkmcnt(0)" ::: "memory");
  __builtin_amdgcn_sched_barrier(0);

  // ---------------- phase 2: stage D, [16x256]@[256x128] f16 MFMA ----------
  const half8* g3fp = (const half8*)gw3f;
  f32x4 dacc[8];
  #pragma unroll
  for (int n = 0; n < 8; ++n) dacc[n] = (f32x4){0.f,0.f,0.f,0.f};

  #pragma unroll
  for (int kt = 0; kt < 8; ++kt){
    half8 afr = *(const half8*)&catl[wid][col][kt*32 + g4*8];
    #pragma unroll
    for (int n = 0; n < 8; ++n)
      dacc[n] = __builtin_amdgcn_mfma_f32_16x16x32_f16(afr, g3fp[(kt*8+n)*64 + lane], dacc[n], 0, 0, 0);
  }

  // store: row = pair (g4*4 + r), col = n*16 + col, with relu
  #pragma unroll
  for (int n = 0; n < 8; ++n)
    #pragma unroll
    for (int r = 0; r < 4; ++r)
      outp[(size_t)(pgrp + g4*4 + r)*D_ + n*16 + col] = fmaxf(dacc[n][r], 0.f);
}

// ---------------------------------------------------------------------------
// output = h_local + s_global
// ---------------------------------------------------------------------------
__global__ void final_add_kernel(float* __restrict__ dout){
  int i = blockIdx.x*blockDim.x + threadIdx.x;
  const int n4 = (B_*L_*D_)/4;
  if (i < n4){
    float4* o = (float4*)dout;
    const float4* s = (const float4*)(dout + B_*L_*D_);
    float4 a = o[i], b = s[i];
    a.x += b.x; a.y += b.y; a.z += b.z; a.w += b.w;
    o[i] = a;
  }
}

extern "C" void kernel_launch(void* const* d_in, const int* in_sizes, int n_in,
                              void* d_out, int out_size, void* d_ws, size_t ws_size,
                              hipStream_t stream)
{
  const int*   inputs  = (const int*)  d_in[0];
  const int*   adj     = (const int*)  d_in[1];
  const int*   mask    = (const int*)  d_in[2];
  const int*   item    = (const int*)  d_in[3];
  const float* emb     = (const float*)d_in[4];
  const int*   adj_all = (const int*)  d_in[5];
  const float* num_w   = (const float*)d_in[6];
  const float* a0      = (const float*)d_in[7];
  const float* a1      = (const float*)d_in[8];
  const float* a2      = (const float*)d_in[9];
  const float* a3      = (const float*)d_in[10];
  const float* gw1     = (const float*)d_in[11];  // [2][129][128]
  const float* gw2     = (const float*)d_in[12];  // [2][128]
  const float* gw3     = (const float*)d_in[13];  // [2][256][128]

  float* out     = (float*)d_out;
  float* hlocal  = out;
  float* sglobal = out + B_*L_*D_;

  char* ws = (char*)d_ws;
  size_t off = 0;
  auto alloc = [&](size_t bytes)->char*{
    char* pp = ws + off; off += (bytes + 255) & ~(size_t)255; return pp;
  };
  float*    sum_it = (float*)alloc((size_t)B_*D_*sizeof(float));
  int*      n1     = (int*)  alloc((size_t)B_*L_*S_*sizeof(int));
  float*    w0     = (float*)alloc((size_t)B_*L_*S_*sizeof(float));
  int*      n2     = (int*)  alloc((size_t)B_*L_*S_*S_*sizeof(int));
  float*    w1     = (float*)alloc((size_t)B_*L_*S_*S_*sizeof(float));
  float*    out0   = (float*)alloc((size_t)B_*L_*D_*sizeof(float));
  float*    out1   = (float*)alloc((size_t)B_*L_*S_*D_*sizeof(float));
  short*    gw1f   = (short*)alloc((size_t)2*16384*sizeof(short));
  _Float16* gw3f   = (_Float16*)alloc((size_t)2*32768*sizeof(_Float16));

  prep_gw1frag_kernel<<<dim3(8,2), 256, 0, stream>>>(gw1, gw1f);
  prep_gw3frag_kernel<<<dim3(16,2), 256, 0, stream>>>(gw3, gw3f);
  local_agg_kernel<<<B_, 256, 0, stream>>>(inputs, adj, emb, a0, a1, a2, a3, hlocal);
  sum_item_kernel<<<B_, 128, 0, stream>>>(item, mask, emb, sum_it);
  build_nbr_kernel<<<(B_*L_*S_ + 255)/256, 256, 0, stream>>>(inputs, B_*L_*S_, adj_all, num_w, n1, w0);
  build_nbr_kernel<<<(B_*L_*S_*S_ + 255)/256, 256, 0, stream>>>(n1, B_*L_*S_*S_, adj_all, num_w, n2, w1);

  // hop0, hp=0: sv=emb[inputs], nv=emb[n1]          -> out0 [6400,128]
  gagg_mfma_kernel<true,true><<<(B_*L_)/64, 256, 0, stream>>>(
      emb, inputs, nullptr, n1, nullptr, w0, sum_it,
      gw1f, gw1 + 128*128, gw2, gw3f, out0, L_);
  // hop0, hp=1: sv=emb[n1], nv=emb[n2]              -> out1 [76800,128]
  gagg_mfma_kernel<true,true><<<(B_*L_*S_)/64, 256, 0, stream>>>(
      emb, n1, nullptr, n2, nullptr, w1, sum_it,
      gw1f, gw1 + 128*128, gw2, gw3f, out1, L_*S_);
  // hop1, hp=0: sv=out0, nv=out1 (hop-0 weights)    -> s_global [6400,128]
  gagg_mfma_kernel<false,false><<<(B_*L_)/64, 256, 0, stream>>>(
      emb, nullptr, out0, nullptr, out1, w0, sum_it,
      gw1f + 16384, gw1 + 129*128 + 128*128, gw2 + 128, gw3f + 32768,
      sglobal, L_);

  final_add_kernel<<<((B_*L_*D_/4) + 255)/256, 256, 0, stream>>>(out);
}

// Round 5
// 593.835 us; speedup vs baseline: 1.4363x; 1.4363x over previous
//
#include <hip/hip_runtime.h>
#include <hip/hip_bf16.h>
#include <math.h>

#define B_ 128
#define L_ 50
#define D_ 128
#define S_ 12
#define NEG_INF_ -9e15f

typedef __attribute__((ext_vector_type(8))) short short8;
typedef __attribute__((ext_vector_type(8))) _Float16 half8;
typedef __attribute__((ext_vector_type(4))) float f32x4;

static __device__ __forceinline__ float4 ld4(const float* p){ return *(const float4*)p; }
static __device__ __forceinline__ float2 ld2(const float* p){ return *(const float2*)p; }
static __device__ __forceinline__ float lrelu(float x){ return x >= 0.f ? x : 0.2f*x; }
static __device__ __forceinline__ short f2bf(float x){
  return __builtin_bit_cast(short, __float2bfloat16(x));   // RNE
}
static __device__ __forceinline__ unsigned pack2h(float a, float b){
  union { _Float16 h[2]; unsigned u; } v;
  v.h[0] = (_Float16)a; v.h[1] = (_Float16)b; return v.u;
}

// ---------------------------------------------------------------------------
// Local aggregator: 4-edge-type GAT over the session graph. One block per b.
// ---------------------------------------------------------------------------
__global__ __launch_bounds__(256) void local_agg_kernel(
    const int* __restrict__ inputs, const int* __restrict__ adj,
    const float* __restrict__ emb,
    const float* __restrict__ a0, const float* __restrict__ a1,
    const float* __restrict__ a2, const float* __restrict__ a3,
    float* __restrict__ hlocal_out)
{
  __shared__ float hs[L_][129];
  __shared__ float alds[4][129];
  __shared__ float att[L_][51];
  const int b = blockIdx.x, tid = threadIdx.x;

  if (tid < 128){
    alds[0][tid] = a0[tid]; alds[1][tid] = a1[tid];
    alds[2][tid] = a2[tid]; alds[3][tid] = a3[tid];
  }
  for (int i = tid; i < L_*D_; i += 256){
    int r = i >> 7, d = i & 127;
    hs[r][d] = emb[(size_t)inputs[b*L_ + r]*D_ + d];
  }
  __syncthreads();

  for (int pth = tid; pth < L_*L_; pth += 256){
    int i = pth / L_, j = pth % L_;
    int at = adj[b*L_*L_ + pth];
    float lg = NEG_INF_;
    if (at >= 1 && at <= 4){
      const float* av = alds[at-1];
      float acc = 0.f;
      #pragma unroll 4
      for (int d = 0; d < D_; ++d) acc = fmaf(hs[i][d]*hs[j][d], av[d], acc);
      lg = lrelu(acc);
    }
    att[i][j] = lg;
  }
  __syncthreads();

  if (tid < L_){
    float m = -1e30f;
    for (int j = 0; j < L_; ++j) m = fmaxf(m, att[tid][j]);
    float sum = 0.f;
    for (int j = 0; j < L_; ++j){ float e = expf(att[tid][j]-m); att[tid][j] = e; sum += e; }
    float inv = 1.f/sum;
    for (int j = 0; j < L_; ++j) att[tid][j] *= inv;
  }
  __syncthreads();

  for (int i2 = tid; i2 < L_*D_; i2 += 256){
    int r = i2 >> 7, d = i2 & 127;
    float acc = 0.f;
    #pragma unroll 5
    for (int j = 0; j < L_; ++j) acc = fmaf(att[r][j], hs[j][d], acc);
    hlocal_out[(size_t)b*L_*D_ + i2] = acc;
  }
}

// ---------------------------------------------------------------------------
// Session mean
// ---------------------------------------------------------------------------
__global__ __launch_bounds__(128) void sum_item_kernel(
    const int* __restrict__ item, const int* __restrict__ mask,
    const float* __restrict__ emb, float* __restrict__ sum_it)
{
  const int b = blockIdx.x, d = threadIdx.x;
  float acc = 0.f, cnt = 0.f;
  for (int l = 0; l < L_; ++l){
    float mf = (float)mask[b*L_ + l];
    acc = fmaf(mf, emb[(size_t)item[b*L_+l]*D_ + d], acc);
    cnt += mf;
  }
  sum_it[b*D_ + d] = acc / cnt;
}

// ---------------------------------------------------------------------------
// Neighbor expansion
// ---------------------------------------------------------------------------
__global__ void build_nbr_kernel(const int* __restrict__ src_ids, int n,
                                 const int* __restrict__ adj_all,
                                 const float* __restrict__ num_w,
                                 int* __restrict__ out_ids, float* __restrict__ out_w)
{
  int t = blockIdx.x*blockDim.x + threadIdx.x;
  if (t >= n) return;
  int parent = src_ids[t / S_];
  int s = t % S_;
  out_ids[t] = adj_all[(size_t)parent*S_ + s];
  out_w[t]   = num_w[(size_t)parent*S_ + s];
}

// ---------------------------------------------------------------------------
// Pack gw1[hop][k<128][d] into MFMA B-fragment order (bf16).
// Fragment (t,n): lane l, slot j <- gw1[k = t*32 + (l>>4)*8 + j][n*16 + (l&15)]
// ---------------------------------------------------------------------------
__global__ void prep_gw1frag_kernel(const float* __restrict__ gw1, short* __restrict__ outf){
  int idx = blockIdx.x*256 + threadIdx.x;     // 0..2047 = t(4) x n(8) x lane(64)
  int hop = blockIdx.y;
  int lane = idx & 63, n = (idx >> 6) & 7, t = idx >> 9;
  int g4 = lane >> 4, col = lane & 15;
  const float* g1 = gw1 + (size_t)hop*129*128;
  size_t base = (size_t)hop*16384 + ((size_t)(t*8 + n)*64 + lane)*8;
  #pragma unroll
  for (int j = 0; j < 8; ++j){
    int k = t*32 + g4*8 + j;
    outf[base + j] = f2bf(g1[(size_t)k*128 + n*16 + col]);
  }
}

// ---------------------------------------------------------------------------
// Pack gw3[hop][k<256][d] into MFMA B-fragment order (f16).
// ---------------------------------------------------------------------------
__global__ void prep_gw3frag_kernel(const float* __restrict__ gw3, _Float16* __restrict__ outf){
  int idx = blockIdx.x*256 + threadIdx.x;     // 0..4095 = kt(8) x n(8) x lane(64)
  int hop = blockIdx.y;
  int lane = idx & 63, n = (idx >> 6) & 7, kt = idx >> 9;
  int g4 = lane >> 4, col = lane & 15;
  const float* g3 = gw3 + (size_t)hop*256*128;
  size_t base = (size_t)hop*32768 + ((size_t)(kt*8 + n)*64 + lane)*8;
  #pragma unroll
  for (int j = 0; j < 8; ++j){
    int k = kt*32 + g4*8 + j;
    outf[base + j] = (_Float16)g3[(size_t)k*128 + n*16 + col];
  }
}

// ---------------------------------------------------------------------------
// GlobalAggregator, MFMA v3.
// Variable waves/block (blockDim/64); each WAVE owns one 16-pair group.
// Two configs per launch (uniform per-block select) so the tiny pass A rides
// inside pass B's dispatch. Phase 1 handles pairs 2-at-a-time (2 MFMA chains
// + 16 gather ld4s in flight). Phase 2: stage D = [16x256]@[256x128] f16 MFMA.
// __launch_bounds__(256,2): 256-VGPR budget -> no scratch spill (R4 lesson).
// ---------------------------------------------------------------------------
template<bool SV_IDS, bool NV_IDS>
__global__ __launch_bounds__(256, 2) void gagg_mfma_kernel(
    const float* __restrict__ emb,
    const int* sv_ids0, const float* sv_vals0,
    const int* nv_ids0, const float* nv_vals0,
    const float* nw0, float* outp0, int M0, int nblk0,
    const int* sv_ids1, const float* sv_vals1,
    const int* nv_ids1, const float* nv_vals1,
    const float* nw1, float* outp1, int M1,
    const float* __restrict__ sum_it,
    const short* __restrict__ gw1f, const float* __restrict__ gw1_last,
    const float* __restrict__ gw2,  const _Float16* __restrict__ gw3f)
{
  extern __shared__ _Float16 catl[];          // [waves][16][264]
  const int tid  = threadIdx.x;
  const int wid  = tid >> 6;
  const int lane = tid & 63;
  const int g4   = lane >> 4;
  const int col  = lane & 15;
  const int nwpb = blockDim.x >> 6;

  const bool c1 = ((int)blockIdx.x >= nblk0);
  const int  blk = c1 ? (int)blockIdx.x - nblk0 : (int)blockIdx.x;
  const int*   sv_ids  = c1 ? sv_ids1  : sv_ids0;
  const float* sv_vals = c1 ? sv_vals1 : sv_vals0;
  const int*   nv_ids  = c1 ? nv_ids1  : nv_ids0;
  const float* nv_vals = c1 ? nv_vals1 : nv_vals0;
  const float* nw      = c1 ? nw1      : nw0;
  float*       outp    = c1 ? outp1    : outp0;
  const int    M       = c1 ? M1       : M0;

  const int pgrp = (blk*nwpb + wid) * 16;
  _Float16* cbase = catl + (size_t)wid*16*264;

  const short8* g1fp = (const short8*)gw1f;
  float g2v[8], glv[8];
  #pragma unroll
  for (int n = 0; n < 8; ++n){
    g2v[n] = gw2[n*16 + col];
    glv[n] = gw1_last[n*16 + col];
  }
  const int srow = col;                       // A row = s (12..15 masked)
  const int sc_  = srow < S_ ? srow : 0;

  // ---------------- phase 1: stages B + C, two pairs per iteration --------
  for (int np = 0; np < 16; np += 2){
    const int pA = pgrp + np, pB = pgrp + np + 1;
    const int bA = pA / M,    bB = pB / M;
    const float* sibA = sum_it + bA*D_;
    const float* sibB = sum_it + bB*D_;
    const float* nvrowA = NV_IDS ? emb + (size_t)nv_ids[pA*S_ + sc_]*D_
                                 : nv_vals + ((size_t)pA*S_ + sc_)*D_;
    const float* nvrowB = NV_IDS ? emb + (size_t)nv_ids[pB*S_ + sc_]*D_
                                 : nv_vals + ((size_t)pB*S_ + sc_)*D_;

    f32x4 accA[8], accB[8];
    #pragma unroll
    for (int n = 0; n < 8; ++n){
      accA[n] = (f32x4){0.f,0.f,0.f,0.f};
      accB[n] = (f32x4){0.f,0.f,0.f,0.f};
    }

    #pragma unroll
    for (int t = 0; t < 4; ++t){
      short8 afA = (short8){0,0,0,0,0,0,0,0};
      short8 afB = (short8){0,0,0,0,0,0,0,0};
      if (srow < S_){
        const int k0 = t*32 + g4*8;
        float4 sa0 = ld4(sibA + k0),   sa1 = ld4(sibA + k0 + 4);
        float4 va0 = ld4(nvrowA + k0), va1 = ld4(nvrowA + k0 + 4);
        float4 sb0 = ld4(sibB + k0),   sb1 = ld4(sibB + k0 + 4);
        float4 vb0 = ld4(nvrowB + k0), vb1 = ld4(nvrowB + k0 + 4);
        afA[0] = f2bf(sa0.x*va0.x); afA[1] = f2bf(sa0.y*va0.y);
        afA[2] = f2bf(sa0.z*va0.z); afA[3] = f2bf(sa0.w*va0.w);
        afA[4] = f2bf(sa1.x*va1.x); afA[5] = f2bf(sa1.y*va1.y);
        afA[6] = f2bf(sa1.z*va1.z); afA[7] = f2bf(sa1.w*va1.w);
        afB[0] = f2bf(sb0.x*vb0.x); afB[1] = f2bf(sb0.y*vb0.y);
        afB[2] = f2bf(sb0.z*vb0.z); afB[3] = f2bf(sb0.w*vb0.w);
        afB[4] = f2bf(sb1.x*vb1.x); afB[5] = f2bf(sb1.y*vb1.y);
        afB[6] = f2bf(sb1.z*vb1.z); afB[7] = f2bf(sb1.w*vb1.w);
      }
      #pragma unroll
      for (int n = 0; n < 8; ++n){
        short8 bf = g1fp[(t*8+n)*64 + lane];
        accA[n] = __builtin_amdgcn_mfma_f32_16x16x32_bf16(afA, bf, accA[n], 0, 0, 0);
        accB[n] = __builtin_amdgcn_mfma_f32_16x16x32_bf16(afB, bf, accB[n], 0, 0, 0);
      }
    }

    // nw rank-1 (fp32) + scores + softmax, per pair
    float wA[S_], wB[S_];
    #pragma unroll
    for (int u = 0; u < 2; ++u){
      const f32x4* acc = u ? accB : accA;
      const int p = u ? pB : pA;
      float* w = u ? wB : wA;
      float nwv[4];
      #pragma unroll
      for (int r = 0; r < 4; ++r){
        int s = g4*4 + r;
        nwv[r] = nw[p*S_ + (s < S_ ? s : 0)];
      }
      float sc4[4];
      #pragma unroll
      for (int r = 0; r < 4; ++r){
        float pr = 0.f;
        #pragma unroll
        for (int n = 0; n < 8; ++n){
          float tv = acc[n][r] + nwv[r]*glv[n];
          pr = fmaf(lrelu(tv), g2v[n], pr);
        }
        pr += __shfl_xor(pr, 1); pr += __shfl_xor(pr, 2);
        pr += __shfl_xor(pr, 4); pr += __shfl_xor(pr, 8);
        sc4[r] = pr;
      }
      float ss[S_];
      #pragma unroll
      for (int grp = 0; grp < 3; ++grp)
        #pragma unroll
        for (int r = 0; r < 4; ++r)
          ss[grp*4 + r] = __shfl(sc4[r], grp*16);
      float m = -1e30f;
      #pragma unroll
      for (int s = 0; s < S_; ++s) m = fmaxf(m, ss[s]);
      float sum = 0.f;
      #pragma unroll
      for (int s = 0; s < S_; ++s){ ss[s] = expf(ss[s]-m); sum += ss[s]; }
      float inv = 1.f/sum;
      #pragma unroll
      for (int s = 0; s < S_; ++s) w[s] = ss[s]*inv;
    }

    // stage C: attn-weighted nv + sv, both pairs interleaved (24 row loads)
    float2 aggA = {0.f,0.f}, aggB = {0.f,0.f};
    #pragma unroll
    for (int s = 0; s < S_; ++s){
      const float* rA = NV_IDS ? emb + (size_t)nv_ids[pA*S_+s]*D_
                               : nv_vals + ((size_t)pA*S_+s)*D_;
      const float* rB = NV_IDS ? emb + (size_t)nv_ids[pB*S_+s]*D_
                               : nv_vals + ((size_t)pB*S_+s)*D_;
      float2 vA = ld2(rA + 2*lane);
      float2 vB = ld2(rB + 2*lane);
      aggA.x = fmaf(wA[s], vA.x, aggA.x); aggA.y = fmaf(wA[s], vA.y, aggA.y);
      aggB.x = fmaf(wB[s], vB.x, aggB.x); aggB.y = fmaf(wB[s], vB.y, aggB.y);
    }
    const float* svrA = SV_IDS ? emb + (size_t)sv_ids[pA]*D_ : sv_vals + (size_t)pA*D_;
    const float* svrB = SV_IDS ? emb + (size_t)sv_ids[pB]*D_ : sv_vals + (size_t)pB*D_;
    float2 svA = ld2(svrA + 2*lane);
    float2 svB = ld2(svrB + 2*lane);

    _Float16* rowA = cbase + (size_t)np*264;
    _Float16* rowB = rowA + 264;
    *(unsigned*)&rowA[2*lane]      = pack2h(svA.x, svA.y);
    *(unsigned*)&rowA[D_ + 2*lane] = pack2h(aggA.x, aggA.y);
    *(unsigned*)&rowB[2*lane]      = pack2h(svB.x, svB.y);
    *(unsigned*)&rowB[D_ + 2*lane] = pack2h(aggB.x, aggB.y);
  }

  asm volatile("s_waitcnt lgkmcnt(0)" ::: "memory");
  __builtin_amdgcn_sched_barrier(0);

  // ---------------- phase 2: stage D, [16x256]@[256x128] f16 MFMA ----------
  const half8* g3fp = (const half8*)gw3f;
  f32x4 dacc[8];
  #pragma unroll
  for (int n = 0; n < 8; ++n) dacc[n] = (f32x4){0.f,0.f,0.f,0.f};

  #pragma unroll
  for (int kt = 0; kt < 8; ++kt){
    half8 afr = *(const half8*)&cbase[(size_t)col*264 + kt*32 + g4*8];
    #pragma unroll
    for (int n = 0; n < 8; ++n)
      dacc[n] = __builtin_amdgcn_mfma_f32_16x16x32_f16(afr, g3fp[(kt*8+n)*64 + lane], dacc[n], 0, 0, 0);
  }

  // store: row = pair (g4*4 + r), col = n*16 + col, with relu
  #pragma unroll
  for (int n = 0; n < 8; ++n)
    #pragma unroll
    for (int r = 0; r < 4; ++r)
      outp[(size_t)(pgrp + g4*4 + r)*D_ + n*16 + col] = fmaxf(dacc[n][r], 0.f);
}

// ---------------------------------------------------------------------------
// output = h_local + s_global
// ---------------------------------------------------------------------------
__global__ void final_add_kernel(float* __restrict__ dout){
  int i = blockIdx.x*blockDim.x + threadIdx.x;
  const int n4 = (B_*L_*D_)/4;
  if (i < n4){
    float4* o = (float4*)dout;
    const float4* s = (const float4*)(dout + B_*L_*D_);
    float4 a = o[i], b = s[i];
    a.x += b.x; a.y += b.y; a.z += b.z; a.w += b.w;
    o[i] = a;
  }
}

extern "C" void kernel_launch(void* const* d_in, const int* in_sizes, int n_in,
                              void* d_out, int out_size, void* d_ws, size_t ws_size,
                              hipStream_t stream)
{
  const int*   inputs  = (const int*)  d_in[0];
  const int*   adj     = (const int*)  d_in[1];
  const int*   mask    = (const int*)  d_in[2];
  const int*   item    = (const int*)  d_in[3];
  const float* emb     = (const float*)d_in[4];
  const int*   adj_all = (const int*)  d_in[5];
  const float* num_w   = (const float*)d_in[6];
  const float* a0      = (const float*)d_in[7];
  const float* a1      = (const float*)d_in[8];
  const float* a2      = (const float*)d_in[9];
  const float* a3      = (const float*)d_in[10];
  const float* gw1     = (const float*)d_in[11];  // [2][129][128]
  const float* gw2     = (const float*)d_in[12];  // [2][128]
  const float* gw3     = (const float*)d_in[13];  // [2][256][128]

  float* out     = (float*)d_out;
  float* hlocal  = out;
  float* sglobal = out + B_*L_*D_;

  char* ws = (char*)d_ws;
  size_t off = 0;
  auto alloc = [&](size_t bytes)->char*{
    char* pp = ws + off; off += (bytes + 255) & ~(size_t)255; return pp;
  };
  float*    sum_it = (float*)alloc((size_t)B_*D_*sizeof(float));
  int*      n1     = (int*)  alloc((size_t)B_*L_*S_*sizeof(int));
  float*    w0     = (float*)alloc((size_t)B_*L_*S_*sizeof(float));
  int*      n2     = (int*)  alloc((size_t)B_*L_*S_*S_*sizeof(int));
  float*    w1     = (float*)alloc((size_t)B_*L_*S_*S_*sizeof(float));
  float*    out0   = (float*)alloc((size_t)B_*L_*D_*sizeof(float));
  float*    out1   = (float*)alloc((size_t)B_*L_*S_*D_*sizeof(float));
  short*    gw1f   = (short*)alloc((size_t)2*16384*sizeof(short));
  _Float16* gw3f   = (_Float16*)alloc((size_t)2*32768*sizeof(_Float16));

  prep_gw1frag_kernel<<<dim3(8,2), 256, 0, stream>>>(gw1, gw1f);
  prep_gw3frag_kernel<<<dim3(16,2), 256, 0, stream>>>(gw3, gw3f);
  local_agg_kernel<<<B_, 256, 0, stream>>>(inputs, adj, emb, a0, a1, a2, a3, hlocal);
  sum_item_kernel<<<B_, 128, 0, stream>>>(item, mask, emb, sum_it);
  build_nbr_kernel<<<(B_*L_*S_ + 255)/256, 256, 0, stream>>>(inputs, B_*L_*S_, adj_all, num_w, n1, w0);
  build_nbr_kernel<<<(B_*L_*S_*S_ + 255)/256, 256, 0, stream>>>(n1, B_*L_*S_*S_, adj_all, num_w, n2, w1);

  // Fused hop0: config0 = pass A (sv=inputs, nv=n1 -> out0, M=50, 100 blocks)
  //             config1 = pass B (sv=n1, nv=n2   -> out1, M=600, 1200 blocks)
  {
    const int nblkA = (B_*L_)/64;        // 100
    const int nblkB = (B_*L_*S_)/64;     // 1200
    const size_t sh = (size_t)4*16*264*sizeof(_Float16);   // 33792 B
    gagg_mfma_kernel<true,true><<<nblkA + nblkB, 256, sh, stream>>>(
        emb,
        inputs, nullptr, n1, nullptr, w0, out0, L_,   nblkA,
        n1,     nullptr, n2, nullptr, w1, out1, L_*S_,
        sum_it, gw1f, gw1 + 128*128, gw2, gw3f);
  }
  // hop1: sv=out0, nv=out1 (hop-0 weights) -> s_global. 1-wave blocks x 400.
  {
    const int nblkC = (B_*L_)/16;        // 400
    const size_t sh = (size_t)1*16*264*sizeof(_Float16);   // 8448 B
    gagg_mfma_kernel<false,false><<<nblkC, 64, sh, stream>>>(
        emb,
        nullptr, out0, nullptr, out1, w0, sglobal, L_, nblkC,
        nullptr, out0, nullptr, out1, w0, sglobal, L_,
        sum_it, gw1f + 16384, gw1 + 129*128 + 128*128, gw2 + 128, gw3f + 32768);
  }

  final_add_kernel<<<((B_*L_*D_/4) + 255)/256, 256, 0, stream>>>(out);
}

// Round 6
// 369.736 us; speedup vs baseline: 2.3068x; 1.6061x over previous
//
#include <hip/hip_runtime.h>
#include <hip/hip_bf16.h>
#include <math.h>

#define B_ 128
#define L_ 50
#define D_ 128
#define S_ 12
#define NEG_INF_ -9e15f

typedef __attribute__((ext_vector_type(8))) short short8;
typedef __attribute__((ext_vector_type(8))) _Float16 half8;
typedef __attribute__((ext_vector_type(4))) float f32x4;

static __device__ __forceinline__ float4 ld4(const float* p){ return *(const float4*)p; }
static __device__ __forceinline__ float2 ld2(const float* p){ return *(const float2*)p; }
static __device__ __forceinline__ float lrelu(float x){ return x >= 0.f ? x : 0.2f*x; }
static __device__ __forceinline__ short f2bf(float x){
  return __builtin_bit_cast(short, __float2bfloat16(x));   // RNE
}
static __device__ __forceinline__ unsigned pack2h(float a, float b){
  union { _Float16 h[2]; unsigned u; } v;
  v.h[0] = (_Float16)a; v.h[1] = (_Float16)b; return v.u;
}

// ---------------------------------------------------------------------------
// Local aggregator: 4-edge-type GAT over the session graph. One block per b.
// ---------------------------------------------------------------------------
__global__ __launch_bounds__(256) void local_agg_kernel(
    const int* __restrict__ inputs, const int* __restrict__ adj,
    const float* __restrict__ emb,
    const float* __restrict__ a0, const float* __restrict__ a1,
    const float* __restrict__ a2, const float* __restrict__ a3,
    float* __restrict__ hlocal_out)
{
  __shared__ float hs[L_][129];
  __shared__ float alds[4][129];
  __shared__ float att[L_][51];
  const int b = blockIdx.x, tid = threadIdx.x;

  if (tid < 128){
    alds[0][tid] = a0[tid]; alds[1][tid] = a1[tid];
    alds[2][tid] = a2[tid]; alds[3][tid] = a3[tid];
  }
  for (int i = tid; i < L_*D_; i += 256){
    int r = i >> 7, d = i & 127;
    hs[r][d] = emb[(size_t)inputs[b*L_ + r]*D_ + d];
  }
  __syncthreads();

  for (int pth = tid; pth < L_*L_; pth += 256){
    int i = pth / L_, j = pth % L_;
    int at = adj[b*L_*L_ + pth];
    float lg = NEG_INF_;
    if (at >= 1 && at <= 4){
      const float* av = alds[at-1];
      float acc = 0.f;
      #pragma unroll 4
      for (int d = 0; d < D_; ++d) acc = fmaf(hs[i][d]*hs[j][d], av[d], acc);
      lg = lrelu(acc);
    }
    att[i][j] = lg;
  }
  __syncthreads();

  if (tid < L_){
    float m = -1e30f;
    for (int j = 0; j < L_; ++j) m = fmaxf(m, att[tid][j]);
    float sum = 0.f;
    for (int j = 0; j < L_; ++j){ float e = expf(att[tid][j]-m); att[tid][j] = e; sum += e; }
    float inv = 1.f/sum;
    for (int j = 0; j < L_; ++j) att[tid][j] *= inv;
  }
  __syncthreads();

  for (int i2 = tid; i2 < L_*D_; i2 += 256){
    int r = i2 >> 7, d = i2 & 127;
    float acc = 0.f;
    #pragma unroll 5
    for (int j = 0; j < L_; ++j) acc = fmaf(att[r][j], hs[j][d], acc);
    hlocal_out[(size_t)b*L_*D_ + i2] = acc;
  }
}

// ---------------------------------------------------------------------------
// Session mean
// ---------------------------------------------------------------------------
__global__ __launch_bounds__(128) void sum_item_kernel(
    const int* __restrict__ item, const int* __restrict__ mask,
    const float* __restrict__ emb, float* __restrict__ sum_it)
{
  const int b = blockIdx.x, d = threadIdx.x;
  float acc = 0.f, cnt = 0.f;
  for (int l = 0; l < L_; ++l){
    float mf = (float)mask[b*L_ + l];
    acc = fmaf(mf, emb[(size_t)item[b*L_+l]*D_ + d], acc);
    cnt += mf;
  }
  sum_it[b*D_ + d] = acc / cnt;
}

// ---------------------------------------------------------------------------
// Neighbor expansion
// ---------------------------------------------------------------------------
__global__ void build_nbr_kernel(const int* __restrict__ src_ids, int n,
                                 const int* __restrict__ adj_all,
                                 const float* __restrict__ num_w,
                                 int* __restrict__ out_ids, float* __restrict__ out_w)
{
  int t = blockIdx.x*blockDim.x + threadIdx.x;
  if (t >= n) return;
  int parent = src_ids[t / S_];
  int s = t % S_;
  out_ids[t] = adj_all[(size_t)parent*S_ + s];
  out_w[t]   = num_w[(size_t)parent*S_ + s];
}

// ---------------------------------------------------------------------------
// Pack gw1[hop][k<128][d] into MFMA B-fragment order (bf16).
// Fragment (t,n): lane l, slot j <- gw1[k = t*32 + (l>>4)*8 + j][n*16 + (l&15)]
// ---------------------------------------------------------------------------
__global__ void prep_gw1frag_kernel(const float* __restrict__ gw1, short* __restrict__ outf){
  int idx = blockIdx.x*256 + threadIdx.x;     // 0..2047 = t(4) x n(8) x lane(64)
  int hop = blockIdx.y;
  int lane = idx & 63, n = (idx >> 6) & 7, t = idx >> 9;
  int g4 = lane >> 4, col = lane & 15;
  const float* g1 = gw1 + (size_t)hop*129*128;
  size_t base = (size_t)hop*16384 + ((size_t)(t*8 + n)*64 + lane)*8;
  #pragma unroll
  for (int j = 0; j < 8; ++j){
    int k = t*32 + g4*8 + j;
    outf[base + j] = f2bf(g1[(size_t)k*128 + n*16 + col]);
  }
}

// ---------------------------------------------------------------------------
// Pack gw3[hop][k<256][d] into MFMA B-fragment order (f16).
// ---------------------------------------------------------------------------
__global__ void prep_gw3frag_kernel(const float* __restrict__ gw3, _Float16* __restrict__ outf){
  int idx = blockIdx.x*256 + threadIdx.x;     // 0..4095 = kt(8) x n(8) x lane(64)
  int hop = blockIdx.y;
  int lane = idx & 63, n = (idx >> 6) & 7, kt = idx >> 9;
  int g4 = lane >> 4, col = lane & 15;
  const float* g3 = gw3 + (size_t)hop*256*128;
  size_t base = (size_t)hop*32768 + ((size_t)(kt*8 + n)*64 + lane)*8;
  #pragma unroll
  for (int j = 0; j < 8; ++j){
    int k = kt*32 + g4*8 + j;
    outf[base + j] = (_Float16)g3[(size_t)k*128 + n*16 + col];
  }
}

// ---------------------------------------------------------------------------
// GlobalAggregator, MFMA v4.
// Variable waves/block; each WAVE owns one 16-pair group, pairs processed
// ONE at a time (R5 lesson: 2-pair interleave exceeds the VGPR file and
// spills 140MB of scratch -> FETCH/WRITE explosion; single-pair fits).
// Two configs per launch so tiny pass A rides in pass B's dispatch.
// Phase 2: stage D = [16x256]@[256x128] f16 MFMA, gw3 frags from L2.
// ---------------------------------------------------------------------------
template<bool SV_IDS, bool NV_IDS>
__global__ __launch_bounds__(256, 2) void gagg_mfma_kernel(
    const float* __restrict__ emb,
    const int* sv_ids0, const float* sv_vals0,
    const int* nv_ids0, const float* nv_vals0,
    const float* nw0, float* outp0, int M0, int nblk0,
    const int* sv_ids1, const float* sv_vals1,
    const int* nv_ids1, const float* nv_vals1,
    const float* nw1, float* outp1, int M1,
    const float* __restrict__ sum_it,
    const short* __restrict__ gw1f, const float* __restrict__ gw1_last,
    const float* __restrict__ gw2,  const _Float16* __restrict__ gw3f)
{
  extern __shared__ _Float16 catl[];          // [waves][16][264]
  const int tid  = threadIdx.x;
  const int wid  = tid >> 6;
  const int lane = tid & 63;
  const int g4   = lane >> 4;
  const int col  = lane & 15;
  const int nwpb = blockDim.x >> 6;

  const bool c1 = ((int)blockIdx.x >= nblk0);
  const int  blk = c1 ? (int)blockIdx.x - nblk0 : (int)blockIdx.x;
  const int*   sv_ids  = c1 ? sv_ids1  : sv_ids0;
  const float* sv_vals = c1 ? sv_vals1 : sv_vals0;
  const int*   nv_ids  = c1 ? nv_ids1  : nv_ids0;
  const float* nv_vals = c1 ? nv_vals1 : nv_vals0;
  const float* nw      = c1 ? nw1      : nw0;
  float*       outp    = c1 ? outp1    : outp0;
  const int    M       = c1 ? M1       : M0;

  const int pgrp = (blk*nwpb + wid) * 16;
  _Float16* cbase = catl + (size_t)wid*16*264;

  const short8* g1fp = (const short8*)gw1f;
  float g2v[8], glv[8];
  #pragma unroll
  for (int n = 0; n < 8; ++n){
    g2v[n] = gw2[n*16 + col];
    glv[n] = gw1_last[n*16 + col];
  }
  const int srow = col;                       // A row = s (12..15 masked)
  const int sc_  = srow < S_ ? srow : 0;

  // ---------------- phase 1: stages B + C, one pair at a time -------------
  for (int np = 0; np < 16; ++np){
    const int p = pgrp + np;
    const int b = p / M;
    const float* sib = sum_it + b*D_;
    const float* nvrow = NV_IDS ? emb + (size_t)nv_ids[p*S_ + sc_]*D_
                                : nv_vals + ((size_t)p*S_ + sc_)*D_;

    f32x4 acc[8];
    #pragma unroll
    for (int n = 0; n < 8; ++n) acc[n] = (f32x4){0.f,0.f,0.f,0.f};

    #pragma unroll
    for (int t = 0; t < 4; ++t){
      short8 af = (short8){0,0,0,0,0,0,0,0};
      if (srow < S_){
        const int k0 = t*32 + g4*8;
        float4 s0 = ld4(sib + k0),   s1 = ld4(sib + k0 + 4);
        float4 v0 = ld4(nvrow + k0), v1 = ld4(nvrow + k0 + 4);
        af[0] = f2bf(s0.x*v0.x); af[1] = f2bf(s0.y*v0.y);
        af[2] = f2bf(s0.z*v0.z); af[3] = f2bf(s0.w*v0.w);
        af[4] = f2bf(s1.x*v1.x); af[5] = f2bf(s1.y*v1.y);
        af[6] = f2bf(s1.z*v1.z); af[7] = f2bf(s1.w*v1.w);
      }
      #pragma unroll
      for (int n = 0; n < 8; ++n)
        acc[n] = __builtin_amdgcn_mfma_f32_16x16x32_bf16(af, g1fp[(t*8+n)*64 + lane], acc[n], 0, 0, 0);
    }

    // nw rank-1 (fp32) + scores
    float nwv[4];
    #pragma unroll
    for (int r = 0; r < 4; ++r){
      int s = g4*4 + r;
      nwv[r] = nw[p*S_ + (s < S_ ? s : 0)];
    }
    float sc4[4];
    #pragma unroll
    for (int r = 0; r < 4; ++r){
      float pr = 0.f;
      #pragma unroll
      for (int n = 0; n < 8; ++n){
        float tv = acc[n][r] + nwv[r]*glv[n];
        pr = fmaf(lrelu(tv), g2v[n], pr);
      }
      pr += __shfl_xor(pr, 1); pr += __shfl_xor(pr, 2);
      pr += __shfl_xor(pr, 4); pr += __shfl_xor(pr, 8);
      sc4[r] = pr;
    }
    float w[S_];
    {
      float ss[S_];
      #pragma unroll
      for (int grp = 0; grp < 3; ++grp)
        #pragma unroll
        for (int r = 0; r < 4; ++r)
          ss[grp*4 + r] = __shfl(sc4[r], grp*16);
      float m = -1e30f;
      #pragma unroll
      for (int s = 0; s < S_; ++s) m = fmaxf(m, ss[s]);
      float sum = 0.f;
      #pragma unroll
      for (int s = 0; s < S_; ++s){ ss[s] = expf(ss[s]-m); sum += ss[s]; }
      float inv = 1.f/sum;
      #pragma unroll
      for (int s = 0; s < S_; ++s) w[s] = ss[s]*inv;
    }

    // stage C: attn-weighted nv + sv -> f16 catl row in LDS
    float2 agg = {0.f, 0.f};
    #pragma unroll
    for (int s = 0; s < S_; ++s){
      const float* row = NV_IDS ? emb + (size_t)nv_ids[p*S_+s]*D_
                                : nv_vals + ((size_t)p*S_+s)*D_;
      float2 v = ld2(row + 2*lane);
      agg.x = fmaf(w[s], v.x, agg.x);
      agg.y = fmaf(w[s], v.y, agg.y);
    }
    const float* svrow = SV_IDS ? emb + (size_t)sv_ids[p]*D_
                                : sv_vals + (size_t)p*D_;
    float2 sv2 = ld2(svrow + 2*lane);

    _Float16* rowp = cbase + (size_t)np*264;
    *(unsigned*)&rowp[2*lane]      = pack2h(sv2.x, sv2.y);
    *(unsigned*)&rowp[D_ + 2*lane] = pack2h(agg.x, agg.y);
  }

  asm volatile("s_waitcnt lgkmcnt(0)" ::: "memory");
  __builtin_amdgcn_sched_barrier(0);

  // ---------------- phase 2: stage D, [16x256]@[256x128] f16 MFMA ----------
  const half8* g3fp = (const half8*)gw3f;
  f32x4 dacc[8];
  #pragma unroll
  for (int n = 0; n < 8; ++n) dacc[n] = (f32x4){0.f,0.f,0.f,0.f};

  #pragma unroll
  for (int kt = 0; kt < 8; ++kt){
    half8 afr = *(const half8*)&cbase[(size_t)col*264 + kt*32 + g4*8];
    #pragma unroll
    for (int n = 0; n < 8; ++n)
      dacc[n] = __builtin_amdgcn_mfma_f32_16x16x32_f16(afr, g3fp[(kt*8+n)*64 + lane], dacc[n], 0, 0, 0);
  }

  // store: row = pair (g4*4 + r), col = n*16 + col, with relu
  #pragma unroll
  for (int n = 0; n < 8; ++n)
    #pragma unroll
    for (int r = 0; r < 4; ++r)
      outp[(size_t)(pgrp + g4*4 + r)*D_ + n*16 + col] = fmaxf(dacc[n][r], 0.f);
}

// ---------------------------------------------------------------------------
// output = h_local + s_global
// ---------------------------------------------------------------------------
__global__ void final_add_kernel(float* __restrict__ dout){
  int i = blockIdx.x*blockDim.x + threadIdx.x;
  const int n4 = (B_*L_*D_)/4;
  if (i < n4){
    float4* o = (float4*)dout;
    const float4* s = (const float4*)(dout + B_*L_*D_);
    float4 a = o[i], b = s[i];
    a.x += b.x; a.y += b.y; a.z += b.z; a.w += b.w;
    o[i] = a;
  }
}

extern "C" void kernel_launch(void* const* d_in, const int* in_sizes, int n_in,
                              void* d_out, int out_size, void* d_ws, size_t ws_size,
                              hipStream_t stream)
{
  const int*   inputs  = (const int*)  d_in[0];
  const int*   adj     = (const int*)  d_in[1];
  const int*   mask    = (const int*)  d_in[2];
  const int*   item    = (const int*)  d_in[3];
  const float* emb     = (const float*)d_in[4];
  const int*   adj_all = (const int*)  d_in[5];
  const float* num_w   = (const float*)d_in[6];
  const float* a0      = (const float*)d_in[7];
  const float* a1      = (const float*)d_in[8];
  const float* a2      = (const float*)d_in[9];
  const float* a3      = (const float*)d_in[10];
  const float* gw1     = (const float*)d_in[11];  // [2][129][128]
  const float* gw2     = (const float*)d_in[12];  // [2][128]
  const float* gw3     = (const float*)d_in[13];  // [2][256][128]

  float* out     = (float*)d_out;
  float* hlocal  = out;
  float* sglobal = out + B_*L_*D_;

  char* ws = (char*)d_ws;
  size_t off = 0;
  auto alloc = [&](size_t bytes)->char*{
    char* pp = ws + off; off += (bytes + 255) & ~(size_t)255; return pp;
  };
  float*    sum_it = (float*)alloc((size_t)B_*D_*sizeof(float));
  int*      n1     = (int*)  alloc((size_t)B_*L_*S_*sizeof(int));
  float*    w0     = (float*)alloc((size_t)B_*L_*S_*sizeof(float));
  int*      n2     = (int*)  alloc((size_t)B_*L_*S_*S_*sizeof(int));
  float*    w1     = (float*)alloc((size_t)B_*L_*S_*S_*sizeof(float));
  float*    out0   = (float*)alloc((size_t)B_*L_*D_*sizeof(float));
  float*    out1   = (float*)alloc((size_t)B_*L_*S_*D_*sizeof(float));
  short*    gw1f   = (short*)alloc((size_t)2*16384*sizeof(short));
  _Float16* gw3f   = (_Float16*)alloc((size_t)2*32768*sizeof(_Float16));

  prep_gw1frag_kernel<<<dim3(8,2), 256, 0, stream>>>(gw1, gw1f);
  prep_gw3frag_kernel<<<dim3(16,2), 256, 0, stream>>>(gw3, gw3f);
  local_agg_kernel<<<B_, 256, 0, stream>>>(inputs, adj, emb, a0, a1, a2, a3, hlocal);
  sum_item_kernel<<<B_, 128, 0, stream>>>(item, mask, emb, sum_it);
  build_nbr_kernel<<<(B_*L_*S_ + 255)/256, 256, 0, stream>>>(inputs, B_*L_*S_, adj_all, num_w, n1, w0);
  build_nbr_kernel<<<(B_*L_*S_*S_ + 255)/256, 256, 0, stream>>>(n1, B_*L_*S_*S_, adj_all, num_w, n2, w1);

  // Fused hop0: config0 = pass A (sv=inputs, nv=n1 -> out0, M=50, 100 blocks)
  //             config1 = pass B (sv=n1, nv=n2   -> out1, M=600, 1200 blocks)
  {
    const int nblkA = (B_*L_)/64;        // 100
    const int nblkB = (B_*L_*S_)/64;     // 1200
    const size_t sh = (size_t)4*16*264*sizeof(_Float16);   // 33792 B
    gagg_mfma_kernel<true,true><<<nblkA + nblkB, 256, sh, stream>>>(
        emb,
        inputs, nullptr, n1, nullptr, w0, out0, L_,   nblkA,
        n1,     nullptr, n2, nullptr, w1, out1, L_*S_,
        sum_it, gw1f, gw1 + 128*128, gw2, gw3f);
  }
  // hop1: sv=out0, nv=out1 (hop-0 weights) -> s_global. 1-wave blocks x 400.
  {
    const int nblkC = (B_*L_)/16;        // 400
    const size_t sh = (size_t)1*16*264*sizeof(_Float16);   // 8448 B
    gagg_mfma_kernel<false,false><<<nblkC, 64, sh, stream>>>(
        emb,
        nullptr, out0, nullptr, out1, w0, sglobal, L_, nblkC,
        nullptr, out0, nullptr, out1, w0, sglobal, L_,
        sum_it, gw1f + 16384, gw1 + 129*128 + 128*128, gw2 + 128, gw3f + 32768);
  }

  final_add_kernel<<<((B_*L_*D_/4) + 255)/256, 256, 0, stream>>>(out);
}

// Round 7
// 347.649 us; speedup vs baseline: 2.4534x; 1.0635x over previous
//
#include <hip/hip_runtime.h>
#include <hip/hip_bf16.h>
#include <math.h>

#define B_ 128
#define L_ 50
#define D_ 128
#define S_ 12
#define NEG_INF_ -9e15f

typedef __attribute__((ext_vector_type(8))) short short8;
typedef __attribute__((ext_vector_type(8))) _Float16 half8;
typedef __attribute__((ext_vector_type(4))) float f32x4;

static __device__ __forceinline__ float4 ld4(const float* p){ return *(const float4*)p; }
static __device__ __forceinline__ float2 ld2(const float* p){ return *(const float2*)p; }
static __device__ __forceinline__ float lrelu(float x){ return x >= 0.f ? x : 0.2f*x; }
static __device__ __forceinline__ short f2bf(float x){
  return __builtin_bit_cast(short, __float2bfloat16(x));   // RNE
}
static __device__ __forceinline__ unsigned pack2h(float a, float b){
  union { _Float16 h[2]; unsigned u; } v;
  v.h[0] = (_Float16)a; v.h[1] = (_Float16)b; return v.u;
}

// ---------------------------------------------------------------------------
// Local aggregator: 4-edge-type GAT. Grid (B, 4): each block owns ~13 rows
// (512 blocks total instead of 128 -> latency spread over the whole chip).
// ---------------------------------------------------------------------------
__global__ __launch_bounds__(256) void local_agg_kernel(
    const int* __restrict__ inputs, const int* __restrict__ adj,
    const float* __restrict__ emb,
    const float* __restrict__ a0, const float* __restrict__ a1,
    const float* __restrict__ a2, const float* __restrict__ a3,
    float* __restrict__ hlocal_out)
{
  __shared__ float hs[L_][129];
  __shared__ float alds[4][129];
  __shared__ float att[13][51];
  const int b = blockIdx.x, tid = threadIdx.x;
  const int r0 = blockIdx.y * 13;
  const int nr = (L_ - r0) < 13 ? (L_ - r0) : 13;

  if (tid < 128){
    alds[0][tid] = a0[tid]; alds[1][tid] = a1[tid];
    alds[2][tid] = a2[tid]; alds[3][tid] = a3[tid];
  }
  for (int i = tid; i < L_*D_; i += 256){
    int r = i >> 7, d = i & 127;
    hs[r][d] = emb[(size_t)inputs[b*L_ + r]*D_ + d];
  }
  __syncthreads();

  for (int pth = tid; pth < nr*L_; pth += 256){
    int i = pth / L_, j = pth % L_;           // i is block-local row
    int at = adj[b*L_*L_ + (r0+i)*L_ + j];
    float lg = NEG_INF_;
    if (at >= 1 && at <= 4){
      const float* av = alds[at-1];
      float acc = 0.f;
      #pragma unroll 4
      for (int d = 0; d < D_; ++d) acc = fmaf(hs[r0+i][d]*hs[j][d], av[d], acc);
      lg = lrelu(acc);
    }
    att[i][j] = lg;
  }
  __syncthreads();

  if (tid < nr){
    float m = -1e30f;
    for (int j = 0; j < L_; ++j) m = fmaxf(m, att[tid][j]);
    float sum = 0.f;
    for (int j = 0; j < L_; ++j){ float e = expf(att[tid][j]-m); att[tid][j] = e; sum += e; }
    float inv = 1.f/sum;
    for (int j = 0; j < L_; ++j) att[tid][j] *= inv;
  }
  __syncthreads();

  for (int i2 = tid; i2 < nr*D_; i2 += 256){
    int r = i2 >> 7, d = i2 & 127;
    float acc = 0.f;
    #pragma unroll 5
    for (int j = 0; j < L_; ++j) acc = fmaf(att[r][j], hs[j][d], acc);
    hlocal_out[(size_t)b*L_*D_ + (size_t)(r0+r)*D_ + d] = acc;
  }
}

// ---------------------------------------------------------------------------
// Session mean
// ---------------------------------------------------------------------------
__global__ __launch_bounds__(128) void sum_item_kernel(
    const int* __restrict__ item, const int* __restrict__ mask,
    const float* __restrict__ emb, float* __restrict__ sum_it)
{
  const int b = blockIdx.x, d = threadIdx.x;
  float acc = 0.f, cnt = 0.f;
  for (int l = 0; l < L_; ++l){
    float mf = (float)mask[b*L_ + l];
    acc = fmaf(mf, emb[(size_t)item[b*L_+l]*D_ + d], acc);
    cnt += mf;
  }
  sum_it[b*D_ + d] = acc / cnt;
}

// ---------------------------------------------------------------------------
// Neighbor expansion
// ---------------------------------------------------------------------------
__global__ void build_nbr_kernel(const int* __restrict__ src_ids, int n,
                                 const int* __restrict__ adj_all,
                                 const float* __restrict__ num_w,
                                 int* __restrict__ out_ids, float* __restrict__ out_w)
{
  int t = blockIdx.x*blockDim.x + threadIdx.x;
  if (t >= n) return;
  int parent = src_ids[t / S_];
  int s = t % S_;
  out_ids[t] = adj_all[(size_t)parent*S_ + s];
  out_w[t]   = num_w[(size_t)parent*S_ + s];
}

// ---------------------------------------------------------------------------
// Pack gw1[hop][k<128][d] into MFMA B-fragment order (bf16).
// Fragment (t,n): lane l, slot j <- gw1[k = t*32 + (l>>4)*8 + j][n*16 + (l&15)]
// ---------------------------------------------------------------------------
__global__ void prep_gw1frag_kernel(const float* __restrict__ gw1, short* __restrict__ outf){
  int idx = blockIdx.x*256 + threadIdx.x;     // 0..2047 = t(4) x n(8) x lane(64)
  int hop = blockIdx.y;
  int lane = idx & 63, n = (idx >> 6) & 7, t = idx >> 9;
  int g4 = lane >> 4, col = lane & 15;
  const float* g1 = gw1 + (size_t)hop*129*128;
  size_t base = (size_t)hop*16384 + ((size_t)(t*8 + n)*64 + lane)*8;
  #pragma unroll
  for (int j = 0; j < 8; ++j){
    int k = t*32 + g4*8 + j;
    outf[base + j] = f2bf(g1[(size_t)k*128 + n*16 + col]);
  }
}

// ---------------------------------------------------------------------------
// Pack gw3[hop][k<256][d] into MFMA B-fragment order (f16).
// ---------------------------------------------------------------------------
__global__ void prep_gw3frag_kernel(const float* __restrict__ gw3, _Float16* __restrict__ outf){
  int idx = blockIdx.x*256 + threadIdx.x;     // 0..4095 = kt(8) x n(8) x lane(64)
  int hop = blockIdx.y;
  int lane = idx & 63, n = (idx >> 6) & 7, kt = idx >> 9;
  int g4 = lane >> 4, col = lane & 15;
  const float* g3 = gw3 + (size_t)hop*256*128;
  size_t base = (size_t)hop*32768 + ((size_t)(kt*8 + n)*64 + lane)*8;
  #pragma unroll
  for (int j = 0; j < 8; ++j){
    int k = kt*32 + g4*8 + j;
    outf[base + j] = (_Float16)g3[(size_t)k*128 + n*16 + col];
  }
}

// ---------------------------------------------------------------------------
// GlobalAggregator, MFMA v5.
// 256-thr/4-wave blocks; each WAVE owns one 16-pair group, single-pair loop
// (R5 lesson: deeper interleave spills). STATIC LDS (R6 lesson: dynamic
// extern-shared dispatch showed 19% occupancy; static 33792B -> 4 blocks/CU
// by LDS, 16 waves/CU). Two configs per launch (pass A rides inside pass B).
// Phase 2: stage D = [16x256]@[256x128] f16 MFMA, gw3 frags from L2.
// ---------------------------------------------------------------------------
template<bool SV_IDS, bool NV_IDS>
__global__ __launch_bounds__(256, 2) void gagg_mfma_kernel(
    const float* __restrict__ emb,
    const int* sv_ids0, const float* sv_vals0,
    const int* nv_ids0, const float* nv_vals0,
    const float* nw0, float* outp0, int M0, int nblk0,
    const int* sv_ids1, const float* sv_vals1,
    const int* nv_ids1, const float* nv_vals1,
    const float* nw1, float* outp1, int M1,
    const float* __restrict__ sum_it,
    const short* __restrict__ gw1f, const float* __restrict__ gw1_last,
    const float* __restrict__ gw2,  const _Float16* __restrict__ gw3f)
{
  __shared__ _Float16 catl[4][16][264];       // 33792 B static
  const int tid  = threadIdx.x;
  const int wid  = tid >> 6;
  const int lane = tid & 63;
  const int g4   = lane >> 4;
  const int col  = lane & 15;

  const bool c1 = ((int)blockIdx.x >= nblk0);
  const int  blk = c1 ? (int)blockIdx.x - nblk0 : (int)blockIdx.x;
  const int*   sv_ids  = c1 ? sv_ids1  : sv_ids0;
  const float* sv_vals = c1 ? sv_vals1 : sv_vals0;
  const int*   nv_ids  = c1 ? nv_ids1  : nv_ids0;
  const float* nv_vals = c1 ? nv_vals1 : nv_vals0;
  const float* nw      = c1 ? nw1      : nw0;
  float*       outp    = c1 ? outp1    : outp0;
  const int    M       = c1 ? M1       : M0;

  const int pgrp = (blk*4 + wid) * 16;
  _Float16* cbase = &catl[wid][0][0];

  const short8* g1fp = (const short8*)gw1f;
  float g2v[8], glv[8];
  #pragma unroll
  for (int n = 0; n < 8; ++n){
    g2v[n] = gw2[n*16 + col];
    glv[n] = gw1_last[n*16 + col];
  }
  const int srow = col;                       // A row = s (12..15 masked)
  const int sc_  = srow < S_ ? srow : 0;

  // ---------------- phase 1: stages B + C, one pair at a time -------------
  for (int np = 0; np < 16; ++np){
    const int p = pgrp + np;
    const int b = p / M;
    const float* sib = sum_it + b*D_;
    const float* nvrow = NV_IDS ? emb + (size_t)nv_ids[p*S_ + sc_]*D_
                                : nv_vals + ((size_t)p*S_ + sc_)*D_;

    f32x4 acc[8];
    #pragma unroll
    for (int n = 0; n < 8; ++n) acc[n] = (f32x4){0.f,0.f,0.f,0.f};

    #pragma unroll
    for (int t = 0; t < 4; ++t){
      short8 af = (short8){0,0,0,0,0,0,0,0};
      if (srow < S_){
        const int k0 = t*32 + g4*8;
        float4 s0 = ld4(sib + k0),   s1 = ld4(sib + k0 + 4);
        float4 v0 = ld4(nvrow + k0), v1 = ld4(nvrow + k0 + 4);
        af[0] = f2bf(s0.x*v0.x); af[1] = f2bf(s0.y*v0.y);
        af[2] = f2bf(s0.z*v0.z); af[3] = f2bf(s0.w*v0.w);
        af[4] = f2bf(s1.x*v1.x); af[5] = f2bf(s1.y*v1.y);
        af[6] = f2bf(s1.z*v1.z); af[7] = f2bf(s1.w*v1.w);
      }
      #pragma unroll
      for (int n = 0; n < 8; ++n)
        acc[n] = __builtin_amdgcn_mfma_f32_16x16x32_bf16(af, g1fp[(t*8+n)*64 + lane], acc[n], 0, 0, 0);
    }

    // nw rank-1 (fp32) + scores
    float nwv[4];
    #pragma unroll
    for (int r = 0; r < 4; ++r){
      int s = g4*4 + r;
      nwv[r] = nw[p*S_ + (s < S_ ? s : 0)];
    }
    float sc4[4];
    #pragma unroll
    for (int r = 0; r < 4; ++r){
      float pr = 0.f;
      #pragma unroll
      for (int n = 0; n < 8; ++n){
        float tv = acc[n][r] + nwv[r]*glv[n];
        pr = fmaf(lrelu(tv), g2v[n], pr);
      }
      pr += __shfl_xor(pr, 1); pr += __shfl_xor(pr, 2);
      pr += __shfl_xor(pr, 4); pr += __shfl_xor(pr, 8);
      sc4[r] = pr;
    }
    float w[S_];
    {
      float ss[S_];
      #pragma unroll
      for (int grp = 0; grp < 3; ++grp)
        #pragma unroll
        for (int r = 0; r < 4; ++r)
          ss[grp*4 + r] = __shfl(sc4[r], grp*16);
      float m = -1e30f;
      #pragma unroll
      for (int s = 0; s < S_; ++s) m = fmaxf(m, ss[s]);
      float sum = 0.f;
      #pragma unroll
      for (int s = 0; s < S_; ++s){ ss[s] = expf(ss[s]-m); sum += ss[s]; }
      float inv = 1.f/sum;
      #pragma unroll
      for (int s = 0; s < S_; ++s) w[s] = ss[s]*inv;
    }

    // stage C: attn-weighted nv + sv -> f16 catl row in LDS
    float2 agg = {0.f, 0.f};
    #pragma unroll
    for (int s = 0; s < S_; ++s){
      const float* row = NV_IDS ? emb + (size_t)nv_ids[p*S_+s]*D_
                                : nv_vals + ((size_t)p*S_+s)*D_;
      float2 v = ld2(row + 2*lane);
      agg.x = fmaf(w[s], v.x, agg.x);
      agg.y = fmaf(w[s], v.y, agg.y);
    }
    const float* svrow = SV_IDS ? emb + (size_t)sv_ids[p]*D_
                                : sv_vals + (size_t)p*D_;
    float2 sv2 = ld2(svrow + 2*lane);

    _Float16* rowp = cbase + (size_t)np*264;
    *(unsigned*)&rowp[2*lane]      = pack2h(sv2.x, sv2.y);
    *(unsigned*)&rowp[D_ + 2*lane] = pack2h(agg.x, agg.y);
  }

  asm volatile("s_waitcnt lgkmcnt(0)" ::: "memory");
  __builtin_amdgcn_sched_barrier(0);

  // ---------------- phase 2: stage D, [16x256]@[256x128] f16 MFMA ----------
  const half8* g3fp = (const half8*)gw3f;
  f32x4 dacc[8];
  #pragma unroll
  for (int n = 0; n < 8; ++n) dacc[n] = (f32x4){0.f,0.f,0.f,0.f};

  #pragma unroll
  for (int kt = 0; kt < 8; ++kt){
    half8 afr = *(const half8*)&cbase[(size_t)col*264 + kt*32 + g4*8];
    #pragma unroll
    for (int n = 0; n < 8; ++n)
      dacc[n] = __builtin_amdgcn_mfma_f32_16x16x32_f16(afr, g3fp[(kt*8+n)*64 + lane], dacc[n], 0, 0, 0);
  }

  // store: row = pair (g4*4 + r), col = n*16 + col, with relu
  #pragma unroll
  for (int n = 0; n < 8; ++n)
    #pragma unroll
    for (int r = 0; r < 4; ++r)
      outp[(size_t)(pgrp + g4*4 + r)*D_ + n*16 + col] = fmaxf(dacc[n][r], 0.f);
}

// ---------------------------------------------------------------------------
// output = h_local + s_global
// ---------------------------------------------------------------------------
__global__ void final_add_kernel(float* __restrict__ dout){
  int i = blockIdx.x*blockDim.x + threadIdx.x;
  const int n4 = (B_*L_*D_)/4;
  if (i < n4){
    float4* o = (float4*)dout;
    const float4* s = (const float4*)(dout + B_*L_*D_);
    float4 a = o[i], b = s[i];
    a.x += b.x; a.y += b.y; a.z += b.z; a.w += b.w;
    o[i] = a;
  }
}

extern "C" void kernel_launch(void* const* d_in, const int* in_sizes, int n_in,
                              void* d_out, int out_size, void* d_ws, size_t ws_size,
                              hipStream_t stream)
{
  const int*   inputs  = (const int*)  d_in[0];
  const int*   adj     = (const int*)  d_in[1];
  const int*   mask    = (const int*)  d_in[2];
  const int*   item    = (const int*)  d_in[3];
  const float* emb     = (const float*)d_in[4];
  const int*   adj_all = (const int*)  d_in[5];
  const float* num_w   = (const float*)d_in[6];
  const float* a0      = (const float*)d_in[7];
  const float* a1      = (const float*)d_in[8];
  const float* a2      = (const float*)d_in[9];
  const float* a3      = (const float*)d_in[10];
  const float* gw1     = (const float*)d_in[11];  // [2][129][128]
  const float* gw2     = (const float*)d_in[12];  // [2][128]
  const float* gw3     = (const float*)d_in[13];  // [2][256][128]

  float* out     = (float*)d_out;
  float* hlocal  = out;
  float* sglobal = out + B_*L_*D_;

  char* ws = (char*)d_ws;
  size_t off = 0;
  auto alloc = [&](size_t bytes)->char*{
    char* pp = ws + off; off += (bytes + 255) & ~(size_t)255; return pp;
  };
  float*    sum_it = (float*)alloc((size_t)B_*D_*sizeof(float));
  int*      n1     = (int*)  alloc((size_t)B_*L_*S_*sizeof(int));
  float*    w0     = (float*)alloc((size_t)B_*L_*S_*sizeof(float));
  int*      n2     = (int*)  alloc((size_t)B_*L_*S_*S_*sizeof(int));
  float*    w1     = (float*)alloc((size_t)B_*L_*S_*S_*sizeof(float));
  float*    out0   = (float*)alloc((size_t)B_*L_*D_*sizeof(float));
  float*    out1   = (float*)alloc((size_t)B_*L_*S_*D_*sizeof(float));
  short*    gw1f   = (short*)alloc((size_t)2*16384*sizeof(short));
  _Float16* gw3f   = (_Float16*)alloc((size_t)2*32768*sizeof(_Float16));

  prep_gw1frag_kernel<<<dim3(8,2), 256, 0, stream>>>(gw1, gw1f);
  prep_gw3frag_kernel<<<dim3(16,2), 256, 0, stream>>>(gw3, gw3f);
  local_agg_kernel<<<dim3(B_,4), 256, 0, stream>>>(inputs, adj, emb, a0, a1, a2, a3, hlocal);
  sum_item_kernel<<<B_, 128, 0, stream>>>(item, mask, emb, sum_it);
  build_nbr_kernel<<<(B_*L_*S_ + 255)/256, 256, 0, stream>>>(inputs, B_*L_*S_, adj_all, num_w, n1, w0);
  build_nbr_kernel<<<(B_*L_*S_*S_ + 255)/256, 256, 0, stream>>>(n1, B_*L_*S_*S_, adj_all, num_w, n2, w1);

  // Fused hop0: config0 = pass A (sv=inputs, nv=n1 -> out0, M=50, 100 blocks)
  //             config1 = pass B (sv=n1, nv=n2   -> out1, M=600, 1200 blocks)
  {
    const int nblkA = (B_*L_)/64;        // 100
    const int nblkB = (B_*L_*S_)/64;     // 1200
    gagg_mfma_kernel<true,true><<<nblkA + nblkB, 256, 0, stream>>>(
        emb,
        inputs, nullptr, n1, nullptr, w0, out0, L_,   nblkA,
        n1,     nullptr, n2, nullptr, w1, out1, L_*S_,
        sum_it, gw1f, gw1 + 128*128, gw2, gw3f);
  }
  // hop1: sv=out0, nv=out1 (hop-0 weights) -> s_global. 100 x 256-thr blocks.
  {
    const int nblkC = (B_*L_)/64;        // 100
    gagg_mfma_kernel<false,false><<<nblkC, 256, 0, stream>>>(
        emb,
        nullptr, out0, nullptr, out1, w0, sglobal, L_, nblkC,
        nullptr, out0, nullptr, out1, w0, sglobal, L_,
        sum_it, gw1f + 16384, gw1 + 129*128 + 128*128, gw2 + 128, gw3f + 32768);
  }

  final_add_kernel<<<((B_*L_*D_/4) + 255)/256, 256, 0, stream>>>(out);
}

// Round 8
// 272.314 us; speedup vs baseline: 3.1321x; 1.2766x over previous
//
#include <hip/hip_runtime.h>
#include <hip/hip_bf16.h>
#include <math.h>

#define B_ 128
#define L_ 50
#define D_ 128
#define S_ 12
#define NEG_INF_ -9e15f

typedef __attribute__((ext_vector_type(8))) short short8;
typedef __attribute__((ext_vector_type(8))) _Float16 half8;
typedef __attribute__((ext_vector_type(4))) float f32x4;

static __device__ __forceinline__ float4 ld4(const float* p){ return *(const float4*)p; }
static __device__ __forceinline__ float2 ld2(const float* p){ return *(const float2*)p; }
static __device__ __forceinline__ float lrelu(float x){ return x >= 0.f ? x : 0.2f*x; }
static __device__ __forceinline__ short f2bf(float x){
  return __builtin_bit_cast(short, __float2bfloat16(x));   // RNE
}
static __device__ __forceinline__ unsigned pack2h(float a, float b){
  union { _Float16 h[2]; unsigned u; } v;
  v.h[0] = (_Float16)a; v.h[1] = (_Float16)b; return v.u;
}

// ---------------------------------------------------------------------------
// Local aggregator: 4-edge-type GAT. Grid (B, 4): each block owns ~13 rows.
// ---------------------------------------------------------------------------
__global__ __launch_bounds__(256) void local_agg_kernel(
    const int* __restrict__ inputs, const int* __restrict__ adj,
    const float* __restrict__ emb,
    const float* __restrict__ a0, const float* __restrict__ a1,
    const float* __restrict__ a2, const float* __restrict__ a3,
    float* __restrict__ hlocal_out)
{
  __shared__ float hs[L_][129];
  __shared__ float alds[4][129];
  __shared__ float att[13][51];
  const int b = blockIdx.x, tid = threadIdx.x;
  const int r0 = blockIdx.y * 13;
  const int nr = (L_ - r0) < 13 ? (L_ - r0) : 13;

  if (tid < 128){
    alds[0][tid] = a0[tid]; alds[1][tid] = a1[tid];
    alds[2][tid] = a2[tid]; alds[3][tid] = a3[tid];
  }
  for (int i = tid; i < L_*D_; i += 256){
    int r = i >> 7, d = i & 127;
    hs[r][d] = emb[(size_t)inputs[b*L_ + r]*D_ + d];
  }
  __syncthreads();

  for (int pth = tid; pth < nr*L_; pth += 256){
    int i = pth / L_, j = pth % L_;
    int at = adj[b*L_*L_ + (r0+i)*L_ + j];
    float lg = NEG_INF_;
    if (at >= 1 && at <= 4){
      const float* av = alds[at-1];
      float acc = 0.f;
      #pragma unroll 4
      for (int d = 0; d < D_; ++d) acc = fmaf(hs[r0+i][d]*hs[j][d], av[d], acc);
      lg = lrelu(acc);
    }
    att[i][j] = lg;
  }
  __syncthreads();

  if (tid < nr){
    float m = -1e30f;
    for (int j = 0; j < L_; ++j) m = fmaxf(m, att[tid][j]);
    float sum = 0.f;
    for (int j = 0; j < L_; ++j){ float e = expf(att[tid][j]-m); att[tid][j] = e; sum += e; }
    float inv = 1.f/sum;
    for (int j = 0; j < L_; ++j) att[tid][j] *= inv;
  }
  __syncthreads();

  for (int i2 = tid; i2 < nr*D_; i2 += 256){
    int r = i2 >> 7, d = i2 & 127;
    float acc = 0.f;
    #pragma unroll 5
    for (int j = 0; j < L_; ++j) acc = fmaf(att[r][j], hs[j][d], acc);
    hlocal_out[(size_t)b*L_*D_ + (size_t)(r0+r)*D_ + d] = acc;
  }
}

// ---------------------------------------------------------------------------
// Session mean
// ---------------------------------------------------------------------------
__global__ __launch_bounds__(128) void sum_item_kernel(
    const int* __restrict__ item, const int* __restrict__ mask,
    const float* __restrict__ emb, float* __restrict__ sum_it)
{
  const int b = blockIdx.x, d = threadIdx.x;
  float acc = 0.f, cnt = 0.f;
  for (int l = 0; l < L_; ++l){
    float mf = (float)mask[b*L_ + l];
    acc = fmaf(mf, emb[(size_t)item[b*L_+l]*D_ + d], acc);
    cnt += mf;
  }
  sum_it[b*D_ + d] = acc / cnt;
}

// ---------------------------------------------------------------------------
// Neighbor expansion
// ---------------------------------------------------------------------------
__global__ void build_nbr_kernel(const int* __restrict__ src_ids, int n,
                                 const int* __restrict__ adj_all,
                                 const float* __restrict__ num_w,
                                 int* __restrict__ out_ids, float* __restrict__ out_w)
{
  int t = blockIdx.x*blockDim.x + threadIdx.x;
  if (t >= n) return;
  int parent = src_ids[t / S_];
  int s = t % S_;
  out_ids[t] = adj_all[(size_t)parent*S_ + s];
  out_w[t]   = num_w[(size_t)parent*S_ + s];
}

// ---------------------------------------------------------------------------
// Pack gw1[hop][k<128][d] into MFMA B-fragment order (bf16).
// Fragment (t,n): lane l, slot j <- gw1[k = t*32 + (l>>4)*8 + j][n*16 + (l&15)]
// ---------------------------------------------------------------------------
__global__ void prep_gw1frag_kernel(const float* __restrict__ gw1, short* __restrict__ outf){
  int idx = blockIdx.x*256 + threadIdx.x;     // 0..2047 = t(4) x n(8) x lane(64)
  int hop = blockIdx.y;
  int lane = idx & 63, n = (idx >> 6) & 7, t = idx >> 9;
  int g4 = lane >> 4, col = lane & 15;
  const float* g1 = gw1 + (size_t)hop*129*128;
  size_t base = (size_t)hop*16384 + ((size_t)(t*8 + n)*64 + lane)*8;
  #pragma unroll
  for (int j = 0; j < 8; ++j){
    int k = t*32 + g4*8 + j;
    outf[base + j] = f2bf(g1[(size_t)k*128 + n*16 + col]);
  }
}

// ---------------------------------------------------------------------------
// Pack gw3[hop][k<256][d] into MFMA B-fragment order (f16).
// ---------------------------------------------------------------------------
__global__ void prep_gw3frag_kernel(const float* __restrict__ gw3, _Float16* __restrict__ outf){
  int idx = blockIdx.x*256 + threadIdx.x;     // 0..4095 = kt(8) x n(8) x lane(64)
  int hop = blockIdx.y;
  int lane = idx & 63, n = (idx >> 6) & 7, kt = idx >> 9;
  int g4 = lane >> 4, col = lane & 15;
  const float* g3 = gw3 + (size_t)hop*256*128;
  size_t base = (size_t)hop*32768 + ((size_t)(kt*8 + n)*64 + lane)*8;
  #pragma unroll
  for (int j = 0; j < 8; ++j){
    int k = kt*32 + g4*8 + j;
    outf[base + j] = (_Float16)g3[(size_t)k*128 + n*16 + col];
  }
}

// ---------------------------------------------------------------------------
// GlobalAggregator, MFMA v6.
// Block = 4 waves x 4 pairs each = 16 pairs. Per pair (one wave):
//   stage B: gather nv rows (full 128 cols), STASH f32 to wave-private
//            nv_lds, build bf16 A-frags, 32x mfma_16x16x32_bf16 vs gw1f (L2).
//   nw rank-1 fp32 + scores + softmax (redundant per lane).
//   stage C: attn-weighted sum FROM LDS (no re-gather), sv gather,
//            f16 catl row into block-shared catl[16][264].
// __syncthreads, then stage D block-coop: [16x256]@[256x128] f16 MFMA,
// each wave owns 2 n-frags. nv_ids software-prefetch rotates one pair ahead.
// R5 lesson: no 2-pair acc interleave (spills). R7 lesson: occupancy is
// reg-capped at ~8 waves/CU; this round shortens the per-pair chain instead.
// ---------------------------------------------------------------------------
template<bool SV_IDS, bool NV_IDS>
__global__ __launch_bounds__(256, 2) void gagg_mfma_kernel(
    const float* __restrict__ emb,
    const int* sv_ids0, const float* sv_vals0,
    const int* nv_ids0, const float* nv_vals0,
    const float* nw0, float* outp0, int M0, int nblk0,
    const int* sv_ids1, const float* sv_vals1,
    const int* nv_ids1, const float* nv_vals1,
    const float* nw1, float* outp1, int M1,
    const float* __restrict__ sum_it,
    const short* __restrict__ gw1f, const float* __restrict__ gw1_last,
    const float* __restrict__ gw2,  const _Float16* __restrict__ gw3f)
{
  __shared__ float    nv_lds[4][S_][132];     // 25344 B (wave-private slices)
  __shared__ _Float16 catl[16][264];          //  8448 B (block-shared)
  const int tid  = threadIdx.x;
  const int wid  = tid >> 6;
  const int lane = tid & 63;
  const int g4   = lane >> 4;
  const int col  = lane & 15;

  const bool c1 = ((int)blockIdx.x >= nblk0);
  const int  blk = c1 ? (int)blockIdx.x - nblk0 : (int)blockIdx.x;
  const int*   sv_ids  = c1 ? sv_ids1  : sv_ids0;
  const float* sv_vals = c1 ? sv_vals1 : sv_vals0;
  const int*   nv_ids  = c1 ? nv_ids1  : nv_ids0;
  const float* nv_vals = c1 ? nv_vals1 : nv_vals0;
  const float* nw      = c1 ? nw1      : nw0;
  float*       outp    = c1 ? outp1    : outp0;
  const int    M       = c1 ? M1       : M0;

  const int pgrp = blk * 16;                  // block's 16 pairs
  const int pw0  = pgrp + wid*4;              // this wave's first pair

  const short8* g1fp = (const short8*)gw1f;
  float g2v[8], glv[8];
  #pragma unroll
  for (int n = 0; n < 8; ++n){
    g2v[n] = gw2[n*16 + col];
    glv[n] = gw1_last[n*16 + col];
  }
  const int srow = col;                       // A row = s (12..15 masked)
  const int sc_  = srow < S_ ? srow : 0;

  // id prefetch (rotate one pair ahead)
  int nvid = NV_IDS ? nv_ids[pw0*S_ + sc_] : 0;

  // ---------------- phase 1: stages B + C, 4 pairs per wave ---------------
  for (int np = 0; np < 4; ++np){
    const int p = pw0 + np;
    const int b = p / M;
    const float* sib = sum_it + b*D_;
    const float* nvrow = NV_IDS ? emb + (size_t)nvid*D_
                                : nv_vals + ((size_t)p*S_ + sc_)*D_;
    if (NV_IDS && np < 3) nvid = nv_ids[(p+1)*S_ + sc_];   // prefetch next

    f32x4 acc[8];
    #pragma unroll
    for (int n = 0; n < 8; ++n) acc[n] = (f32x4){0.f,0.f,0.f,0.f};

    #pragma unroll
    for (int t = 0; t < 4; ++t){
      short8 af = (short8){0,0,0,0,0,0,0,0};
      if (srow < S_){
        const int k0 = t*32 + g4*8;
        float4 s0 = ld4(sib + k0),   s1 = ld4(sib + k0 + 4);
        float4 v0 = ld4(nvrow + k0), v1 = ld4(nvrow + k0 + 4);
        *(float4*)&nv_lds[wid][srow][k0]     = v0;   // stash for stage C
        *(float4*)&nv_lds[wid][srow][k0 + 4] = v1;
        af[0] = f2bf(s0.x*v0.x); af[1] = f2bf(s0.y*v0.y);
        af[2] = f2bf(s0.z*v0.z); af[3] = f2bf(s0.w*v0.w);
        af[4] = f2bf(s1.x*v1.x); af[5] = f2bf(s1.y*v1.y);
        af[6] = f2bf(s1.z*v1.z); af[7] = f2bf(s1.w*v1.w);
      }
      #pragma unroll
      for (int n = 0; n < 8; ++n)
        acc[n] = __builtin_amdgcn_mfma_f32_16x16x32_bf16(af, g1fp[(t*8+n)*64 + lane], acc[n], 0, 0, 0);
    }

    // nw rank-1 (fp32) + scores
    float nwv[4];
    #pragma unroll
    for (int r = 0; r < 4; ++r){
      int s = g4*4 + r;
      nwv[r] = nw[p*S_ + (s < S_ ? s : 0)];
    }
    float sc4[4];
    #pragma unroll
    for (int r = 0; r < 4; ++r){
      float pr = 0.f;
      #pragma unroll
      for (int n = 0; n < 8; ++n){
        float tv = acc[n][r] + nwv[r]*glv[n];
        pr = fmaf(lrelu(tv), g2v[n], pr);
      }
      pr += __shfl_xor(pr, 1); pr += __shfl_xor(pr, 2);
      pr += __shfl_xor(pr, 4); pr += __shfl_xor(pr, 8);
      sc4[r] = pr;
    }
    float w[S_];
    {
      float ss[S_];
      #pragma unroll
      for (int grp = 0; grp < 3; ++grp)
        #pragma unroll
        for (int r = 0; r < 4; ++r)
          ss[grp*4 + r] = __shfl(sc4[r], grp*16);
      float m = -1e30f;
      #pragma unroll
      for (int s = 0; s < S_; ++s) m = fmaxf(m, ss[s]);
      float sum = 0.f;
      #pragma unroll
      for (int s = 0; s < S_; ++s){ ss[s] = expf(ss[s]-m); sum += ss[s]; }
      float inv = 1.f/sum;
      #pragma unroll
      for (int s = 0; s < S_; ++s) w[s] = ss[s]*inv;
    }

    // stage C: attn-weighted nv from LDS stash + sv gather -> catl row
    float2 agg = {0.f, 0.f};
    #pragma unroll
    for (int s = 0; s < S_; ++s){
      float2 v = *(const float2*)&nv_lds[wid][s][2*lane];
      agg.x = fmaf(w[s], v.x, agg.x);
      agg.y = fmaf(w[s], v.y, agg.y);
    }
    const float* svrow = SV_IDS ? emb + (size_t)sv_ids[p]*D_
                                : sv_vals + (size_t)p*D_;
    float2 sv2 = ld2(svrow + 2*lane);

    _Float16* rowp = &catl[wid*4 + np][0];
    *(unsigned*)&rowp[2*lane]      = pack2h(sv2.x, sv2.y);
    *(unsigned*)&rowp[D_ + 2*lane] = pack2h(agg.x, agg.y);
  }

  __syncthreads();

  // ---------------- phase 2: stage D block-coop, wave owns 2 n-frags ------
  const half8* g3fp = (const half8*)gw3f;
  f32x4 dacc[2];
  dacc[0] = (f32x4){0.f,0.f,0.f,0.f};
  dacc[1] = (f32x4){0.f,0.f,0.f,0.f};

  #pragma unroll
  for (int kt = 0; kt < 8; ++kt){
    half8 afr = *(const half8*)&catl[col][kt*32 + g4*8];
    #pragma unroll
    for (int nn = 0; nn < 2; ++nn){
      int n = wid*2 + nn;
      dacc[nn] = __builtin_amdgcn_mfma_f32_16x16x32_f16(afr, g3fp[(kt*8+n)*64 + lane], dacc[nn], 0, 0, 0);
    }
  }

  // store: row = pair (g4*4 + r), col = n*16 + col, with relu
  #pragma unroll
  for (int nn = 0; nn < 2; ++nn){
    int n = wid*2 + nn;
    #pragma unroll
    for (int r = 0; r < 4; ++r)
      outp[(size_t)(pgrp + g4*4 + r)*D_ + n*16 + col] = fmaxf(dacc[nn][r], 0.f);
  }
}

// ---------------------------------------------------------------------------
// output = h_local + s_global
// ---------------------------------------------------------------------------
__global__ void final_add_kernel(float* __restrict__ dout){
  int i = blockIdx.x*blockDim.x + threadIdx.x;
  const int n4 = (B_*L_*D_)/4;
  if (i < n4){
    float4* o = (float4*)dout;
    const float4* s = (const float4*)(dout + B_*L_*D_);
    float4 a = o[i], b = s[i];
    a.x += b.x; a.y += b.y; a.z += b.z; a.w += b.w;
    o[i] = a;
  }
}

extern "C" void kernel_launch(void* const* d_in, const int* in_sizes, int n_in,
                              void* d_out, int out_size, void* d_ws, size_t ws_size,
                              hipStream_t stream)
{
  const int*   inputs  = (const int*)  d_in[0];
  const int*   adj     = (const int*)  d_in[1];
  const int*   mask    = (const int*)  d_in[2];
  const int*   item    = (const int*)  d_in[3];
  const float* emb     = (const float*)d_in[4];
  const int*   adj_all = (const int*)  d_in[5];
  const float* num_w   = (const float*)d_in[6];
  const float* a0      = (const float*)d_in[7];
  const float* a1      = (const float*)d_in[8];
  const float* a2      = (const float*)d_in[9];
  const float* a3      = (const float*)d_in[10];
  const float* gw1     = (const float*)d_in[11];  // [2][129][128]
  const float* gw2     = (const float*)d_in[12];  // [2][128]
  const float* gw3     = (const float*)d_in[13];  // [2][256][128]

  float* out     = (float*)d_out;
  float* hlocal  = out;
  float* sglobal = out + B_*L_*D_;

  char* ws = (char*)d_ws;
  size_t off = 0;
  auto alloc = [&](size_t bytes)->char*{
    char* pp = ws + off; off += (bytes + 255) & ~(size_t)255; return pp;
  };
  float*    sum_it = (float*)alloc((size_t)B_*D_*sizeof(float));
  int*      n1     = (int*)  alloc((size_t)B_*L_*S_*sizeof(int));
  float*    w0     = (float*)alloc((size_t)B_*L_*S_*sizeof(float));
  int*      n2     = (int*)  alloc((size_t)B_*L_*S_*S_*sizeof(int));
  float*    w1     = (float*)alloc((size_t)B_*L_*S_*S_*sizeof(float));
  float*    out0   = (float*)alloc((size_t)B_*L_*D_*sizeof(float));
  float*    out1   = (float*)alloc((size_t)B_*L_*S_*D_*sizeof(float));
  short*    gw1f   = (short*)alloc((size_t)2*16384*sizeof(short));
  _Float16* gw3f   = (_Float16*)alloc((size_t)2*32768*sizeof(_Float16));

  prep_gw1frag_kernel<<<dim3(8,2), 256, 0, stream>>>(gw1, gw1f);
  prep_gw3frag_kernel<<<dim3(16,2), 256, 0, stream>>>(gw3, gw3f);
  local_agg_kernel<<<dim3(B_,4), 256, 0, stream>>>(inputs, adj, emb, a0, a1, a2, a3, hlocal);
  sum_item_kernel<<<B_, 128, 0, stream>>>(item, mask, emb, sum_it);
  build_nbr_kernel<<<(B_*L_*S_ + 255)/256, 256, 0, stream>>>(inputs, B_*L_*S_, adj_all, num_w, n1, w0);
  build_nbr_kernel<<<(B_*L_*S_*S_ + 255)/256, 256, 0, stream>>>(n1, B_*L_*S_*S_, adj_all, num_w, n2, w1);

  // Fused hop0: config0 = pass A (sv=inputs, nv=n1 -> out0, M=50, 400 blocks)
  //             config1 = pass B (sv=n1, nv=n2   -> out1, M=600, 4800 blocks)
  {
    const int nblkA = (B_*L_)/16;        // 400
    const int nblkB = (B_*L_*S_)/16;     // 4800
    gagg_mfma_kernel<true,true><<<nblkA + nblkB, 256, 0, stream>>>(
        emb,
        inputs, nullptr, n1, nullptr, w0, out0, L_,   nblkA,
        n1,     nullptr, n2, nullptr, w1, out1, L_*S_,
        sum_it, gw1f, gw1 + 128*128, gw2, gw3f);
  }
  // hop1: sv=out0, nv=out1 (hop-0 weights) -> s_global. 400 x 16-pair blocks.
  {
    const int nblkC = (B_*L_)/16;        // 400
    gagg_mfma_kernel<false,false><<<nblkC, 256, 0, stream>>>(
        emb,
        nullptr, out0, nullptr, out1, w0, sglobal, L_, nblkC,
        nullptr, out0, nullptr, out1, w0, sglobal, L_,
        sum_it, gw1f + 16384, gw1 + 129*128 + 128*128, gw2 + 128, gw3f + 32768);
  }

  final_add_kernel<<<((B_*L_*D_/4) + 255)/256, 256, 0, stream>>>(out);
}